// Round 3
// baseline (824.205 us; speedup 1.0000x reference)
//
#include <hip/hip_runtime.h>
#include <cstdint>
#include <cstddef>

namespace {

constexpr int Bb = 8;
constexpr int Nn = 2048;
constexpr int Dd = 1024;
constexpr int QB = 32;
constexpr int KVB = 32;
constexpr int NT = Nn / KVB;  // 64 kv tiles

typedef _Float16 half8 __attribute__((ext_vector_type(8)));
typedef float f32x4v __attribute__((ext_vector_type(4)));
typedef float f32x16v __attribute__((ext_vector_type(16)));
typedef unsigned int v2u __attribute__((ext_vector_type(2)));
typedef unsigned int v4u __attribute__((ext_vector_type(4)));

__device__ __forceinline__ float fast_exp2(float x) {
  float r;
  asm("v_exp_f32 %0, %1\n\ts_nop 1" : "=v"(r) : "v"(x));
  return r;
}

// pack two f32 -> one u32 of 2x fp16 (RTZ); src0 -> low 16 bits
__device__ __forceinline__ unsigned cvt2(float a, float b) {
  return __builtin_bit_cast(unsigned, __builtin_amdgcn_cvt_pkrtz(a, b));
}

// LDS layout for the staged 32(kv) x 1024(d) fp16 tile:
// addr(kv,d) = (kv>>2)*8192 + (d>>4)*128
//            + (((kv&3) ^ (((kv>>3)&1)<<1) ^ ((d>>4)&1)) * 32
//            + ((d>>3)&1)*16 + (d&7)*2
// The XOR spreads PV's fixed-kv gathers across all 32 banks.

// staging write offset: granule r, thread tid writes kv = r*4 + ((tid&7)>>1),
// d = (tid>>3)*16 + (tid&1)*8 + (0..7)   (16 bytes, contiguous)
__device__ __forceinline__ unsigned stage_off(int r, int tid) {
  return (unsigned)(r * 8192 + (tid >> 3) * 128 +
                    ((((tid & 7) >> 1) ^ (((r >> 1) & 1) << 1) ^
                      ((tid >> 3) & 1)) *
                     32) +
                    (tid & 1) * 16);
}

// One flash-attention forward (no scale), K == V == Y.
// grid: 512 blocks; bid&7 = batch (XCD-pinned), bid>>3 = q-block of 32 rows.
__global__ __launch_bounds__(512, 2) void flash_fwd(
    const float* __restrict__ Qm, const float* __restrict__ Ym,
    float* __restrict__ Om) {
  __shared__ __attribute__((aligned(16))) char ybuf[2][65536];
  __shared__ float pscr[8][256];
  __shared__ __attribute__((aligned(16))) char Pb[2048];
  __shared__ float smax[2][2][16];
  __shared__ float ssum[2][2][16];
  __shared__ float sscale[32];
  __shared__ float sinvl[32];
  __shared__ int sflag[2];

  const int tid = (int)threadIdx.x;
  const int w = tid >> 6;        // wave 0..7
  const int l = tid & 63;
  const int lm = l & 15;
  const int g = (l >> 4) & 3;
  const int g2 = (l >> 5) & 1;
  const int l31 = l & 31;
  const int qf = w >> 2;         // q sub-block (16 rows)
  const int kvf = (w >> 1) & 1;  // kv sub-block (16 rows)
  const int dh = w & 1;          // d half (512)

  const int bid = (int)blockIdx.x;
  const int batch = bid & 7;
  const int row0 = (bid >> 3) * QB;

  const float* Qb = Qm + (size_t)batch * Nn * Dd;
  const float* Yb = Ym + (size_t)batch * Nn * Dd;
  float* Ob = Om + (size_t)batch * Nn * Dd;

  // ---- Q fragments resident in registers (fp32 -> fp16), B-operand labels:
  // lane: q = lm (col), element (g,i) = d = dh*512 + ks*32 + g*8 + i
  half8 qreg[16];
  {
    const float* qrow = Qb + (size_t)(row0 + qf * 16 + lm) * Dd + dh * 512;
#pragma unroll
    for (int ks = 0; ks < 16; ++ks) {
      const float* p = qrow + ks * 32 + g * 8;
      f32x4v a = *(const f32x4v*)p;
      f32x4v b = *(const f32x4v*)(p + 4);
      v4u pk;
      pk[0] = cvt2(a[0], a[1]);
      pk[1] = cvt2(a[2], a[3]);
      pk[2] = cvt2(b[0], b[1]);
      pk[3] = cvt2(b[2], b[3]);
      qreg[ks] = __builtin_bit_cast(half8, pk);
    }
  }

  // S-phase A-read base: addr(kv = kvf*16+lm, d = dh*512 + g*8) (+ ks*256)
  const unsigned ybase_s =
      (unsigned)((kvf * 4 + (lm >> 2)) * 8192 + (dh * 32 + (g >> 1)) * 128 +
                 (((lm & 3) ^ (((lm >> 3) & 1) << 1) ^ (g >> 1)) * 32) +
                 (g & 1) * 16);

  // ---- prologue: stage tile 0 into ybuf[0]
  {
#pragma unroll
    for (int r = 0; r < 8; ++r) {
      const float* p = Yb + (size_t)(r * 4 + ((tid & 7) >> 1)) * Dd +
                       ((tid >> 3) << 4) + ((tid & 1) << 3);
      f32x4v a = *(const f32x4v*)p;
      f32x4v b = *(const f32x4v*)(p + 4);
      v4u pk;
      pk[0] = cvt2(a[0], a[1]);
      pk[1] = cvt2(a[2], a[3]);
      pk[2] = cvt2(b[0], b[1]);
      pk[3] = cvt2(b[2], b[3]);
      *(v4u*)(&ybuf[0][0] + stage_off(r, tid)) = pk;
    }
  }

  f32x16v Oacc[4];
#pragma unroll
  for (int i = 0; i < 4; ++i) {
#pragma unroll
    for (int j = 0; j < 16; ++j) Oacc[i][j] = 0.0f;
  }

  float m_run = -__builtin_inff();
  float l_run = 0.0f;

  __syncthreads();

  for (int t = 0; t < NT; ++t) {
    const int cur = t & 1;
    const char* ybc = &ybuf[cur][0];
    char* ybn = &ybuf[cur ^ 1][0];
    const float* ynext = Yb + (size_t)(((t + 1) & (NT - 1)) * KVB) * Dd;

    // issue round-A staging loads early (tile t+1, granules 0..3)
    f32x4v ra[8];
#pragma unroll
    for (int r = 0; r < 4; ++r) {
      const float* p = ynext + (size_t)(r * 4 + ((tid & 7) >> 1)) * Dd +
                       ((tid >> 3) << 4) + ((tid & 1) << 3);
      ra[2 * r] = *(const f32x4v*)p;
      ra[2 * r + 1] = *(const f32x4v*)(p + 4);
    }

    // ---- S^T partial (this wave's d-half): D[kv,q] += sum_d Y*Q
    f32x4v acc = {0.0f, 0.0f, 0.0f, 0.0f};
#pragma unroll
    for (int ks = 0; ks < 16; ++ks) {
      half8 av = *(const half8*)(ybc + ybase_s + ks * 256);
      acc = __builtin_amdgcn_mfma_f32_16x16x32_f16(av, qreg[ks], acc, 0, 0, 0);
    }

    // ---- cross d-half reduce
    *(f32x4v*)&pscr[w][l * 4] = acc;
    __syncthreads();  // B1
    acc += *(const f32x4v*)&pscr[w ^ 1][l * 4];

    // per-q tile max over this wave's 16 kv rows (rows kv = g*4 + reg)
    float pm = fmaxf(fmaxf(acc[0], acc[1]), fmaxf(acc[2], acc[3]));
    pm = fmaxf(pm, __shfl_xor(pm, 16));
    pm = fmaxf(pm, __shfl_xor(pm, 32));
    if (dh == 0 && l < 16) smax[qf][kvf][l] = pm;
    __syncthreads();  // B2a

    // write round-A staging to next buffer; issue round-B loads
#pragma unroll
    for (int r = 0; r < 4; ++r) {
      v4u pk;
      pk[0] = cvt2(ra[2 * r][0], ra[2 * r][1]);
      pk[1] = cvt2(ra[2 * r][2], ra[2 * r][3]);
      pk[2] = cvt2(ra[2 * r + 1][0], ra[2 * r + 1][1]);
      pk[3] = cvt2(ra[2 * r + 1][2], ra[2 * r + 1][3]);
      *(v4u*)(ybn + stage_off(r, tid)) = pk;
    }
    f32x4v rb[8];
#pragma unroll
    for (int r = 4; r < 8; ++r) {
      const float* p = ynext + (size_t)(r * 4 + ((tid & 7) >> 1)) * Dd +
                       ((tid >> 3) << 4) + ((tid & 1) << 3);
      rb[2 * (r - 4)] = *(const f32x4v*)p;
      rb[2 * (r - 4) + 1] = *(const f32x4v*)(p + 4);
    }

    // ---- online softmax with defer-max (THR = 8 nats)
    float m_tile = fmaxf(smax[qf][0][lm], smax[qf][1][lm]);
    bool defer = (m_tile <= m_run + 8.0f);
    bool allw = (bool)__all((int)defer);
    float scale = 1.0f;
    if (!allw) {
      float mnew = fmaxf(m_run, m_tile);
      scale = fast_exp2((m_run - mnew) * 1.44269504088896f);
      m_run = mnew;
    }
    float p0 = fast_exp2((acc[0] - m_run) * 1.44269504088896f);
    float p1 = fast_exp2((acc[1] - m_run) * 1.44269504088896f);
    float p2 = fast_exp2((acc[2] - m_run) * 1.44269504088896f);
    float p3 = fast_exp2((acc[3] - m_run) * 1.44269504088896f);
    float ps = (p0 + p1) + (p2 + p3);
    ps += __shfl_xor(ps, 16);
    ps += __shfl_xor(ps, 32);
    if (dh == 0) {
      if (l < 16) ssum[qf][kvf][l] = ps;
      v2u pw;
      pw[0] = cvt2(p0, p1);
      pw[1] = cvt2(p2, p3);
      // P[qrow = qf*16+lm][kv = kvf*16 + g*4 + (0..3)], XOR-swizzled
      unsigned pb = (unsigned)((16 * qf + lm) * 64 + 32 * kvf + 8 * g) ^
                    (unsigned)((lm & 7) << 4);
      *(v2u*)(Pb + pb) = pw;
      if (kvf == 0) {
        if (l < 16) sscale[qf * 16 + l] = scale;
        if (l == 0) sflag[qf] = allw ? 0 : 1;
      }
    }
    __syncthreads();  // B2b

    l_run = l_run * scale + (ssum[qf][0][lm] + ssum[qf][1][lm]);

    if (sflag[0] | sflag[1]) {
#pragma unroll
      for (int reg = 0; reg < 16; ++reg) {
        const int q = (reg & 3) + 8 * (reg >> 2) + 4 * g2;
        const float sc = sscale[q];
#pragma unroll
        for (int df = 0; df < 4; ++df) Oacc[df][reg] *= sc;
      }
    }

    // ---- PV: O[q,d] += sum_kv P[q,kv] * Y[kv,d]  (32x32x16)
    // A = P rows q = l31, elements (g2,i) = kv = ks*16 + g2*8 + i
    // B = Y cols d = (w+8*df)*32 + l31, same kv labels (explicit u16 gathers)
#pragma unroll
    for (int ks = 0; ks < 2; ++ks) {
      unsigned pb = ((unsigned)(l31 * 64 + 32 * ks + 16 * g2)) ^
                    (unsigned)((l31 & 7) << 4);
      half8 pa = *(const half8*)(Pb + pb);
#pragma unroll
      for (int df = 0; df < 4; ++df) {
        const int row = (w + 8 * df) * 2 + (l31 >> 4);      // d>>4
        const int lowb = ((l31 >> 3) & 1) * 16 + (l31 & 7) * 2;
        const int fxor = (g2 << 1) ^ ((l31 >> 4) & 1);
        half8 bv;
#pragma unroll
        for (int i = 0; i < 8; ++i) {
          const int blk = ks * 4 + g2 * 2 + (i >> 2);        // kv>>2
          const int sub = (i & 3) ^ fxor;
          const int addr = blk * 8192 + row * 128 + sub * 32 + lowb;
          bv[i] = *(const _Float16*)(ybc + addr);
        }
        Oacc[df] =
            __builtin_amdgcn_mfma_f32_32x32x16_f16(pa, bv, Oacc[df], 0, 0, 0);
      }
    }

    // write round-B staging
#pragma unroll
    for (int r = 4; r < 8; ++r) {
      const int i = 2 * (r - 4);
      v4u pk;
      pk[0] = cvt2(rb[i][0], rb[i][1]);
      pk[1] = cvt2(rb[i][2], rb[i][3]);
      pk[2] = cvt2(rb[i + 1][0], rb[i + 1][1]);
      pk[3] = cvt2(rb[i + 1][2], rb[i + 1][3]);
      *(v4u*)(ybn + stage_off(r, tid)) = pk;
    }
    __syncthreads();  // B3
  }

  // ---- epilogue: O / l_run -> global
  if (dh == 0 && kvf == 0 && l < 16) sinvl[qf * 16 + l] = 1.0f / l_run;
  __syncthreads();

#pragma unroll
  for (int reg = 0; reg < 16; ++reg) {
    const int q = (reg & 3) + 8 * (reg >> 2) + 4 * g2;
    const float inv = sinvl[q];
    float* orow = Ob + (size_t)(row0 + q) * Dd + l31;
#pragma unroll
    for (int df = 0; df < 4; ++df) {
      orow[(w + 8 * df) * 32] = Oacc[df][reg] * inv;
    }
  }
}

}  // namespace

extern "C" void kernel_launch(void* const* d_in, const int* in_sizes, int n_in,
                              void* d_out, int out_size, void* d_ws,
                              size_t ws_size, hipStream_t stream) {
  (void)in_sizes; (void)n_in; (void)d_ws; (void)ws_size; (void)out_size;
  const float* x = (const float*)d_in[0];
  const float* y = (const float*)d_in[1];
  float* A = (float*)d_out;
  float* Bo = A + (size_t)Bb * Nn * Dd;
  dim3 grid(Bb * (Nn / QB));
  dim3 blk(512);
  // A = attention(Q=x, K=V=y)  [row softmax]
  hipLaunchKernelGGL(flash_fwd, grid, blk, 0, stream, x, y, A);
  // Bout = attention(Q=y, K=V=x)  [col softmax]
  hipLaunchKernelGGL(flash_fwd, grid, blk, 0, stream, y, x, Bo);
}